// Round 8
// baseline (240.338 us; speedup 1.0000x reference)
//
#include <hip/hip_runtime.h>

#define EPS_ 1e-5f
#define BATCH 32
#define CIN 240
#define H_ 56
#define W_ 56
#define HW 3136          // 56*56
#define C1 24            // init_c
#define R_ 9             // ratio-1
#define C2 216           // C1*R_
#define COUT 240

// ---- workspace layout (floats) ----
#define WS_WT   0        // [240][24]  conv1x1 weights, ci-major, BN1 scale folded
#define WS_B1   5760     // [24]       BN1 bias
#define WS_WDW  5784     // [24][9]    dw weights, BN2 scale folded
#define WS_B2   6000     // [24]       BN2 bias
#define WS_INV3 6024     // [216]
#define WS_T3   6240     // [216]
#define WS_T1   8192     // [32][24][3136] t1 tensor (9.63 MB) -- if ws_size permits
#define WS_T1_FLOATS (8192 + BATCH * C1 * HW)

// Fold BN params / transpose weights. Separate tiny dispatch (~3 us): r6
// proved folding this into conv1x1's staging loop perturbs conv's regalloc
// (VGPR 70->48, pipeline collapse, 50->77 us). Keep it separate forever.
__global__ __launch_bounds__(256) void prep_kernel(
    const float* __restrict__ wp,
    const float* __restrict__ g1, const float* __restrict__ b1,
    const float* __restrict__ m1, const float* __restrict__ v1,
    const float* __restrict__ wdw,
    const float* __restrict__ g2, const float* __restrict__ b2,
    const float* __restrict__ m2, const float* __restrict__ v2,
    const float* __restrict__ g3, const float* __restrict__ b3,
    const float* __restrict__ m3, const float* __restrict__ v3,
    float* __restrict__ ws) {
  int i = blockIdx.x * 256 + threadIdx.x;
  if (i < 5760) {
    // transpose w_primary (co-major [24][240]) -> ci-major [240][24], fold BN1
    int ci = i / C1, co = i % C1;
    float s = g1[co] / sqrtf(v1[co] + EPS_);
    ws[WS_WT + ci * C1 + co] = wp[co * CIN + ci] * s;
    if (ci == 0) ws[WS_B1 + co] = b1[co] - m1[co] * s;
  } else if (i < 5760 + C2) {
    int j = i - 5760;           // [0,216): c*9+k
    int c = j / 9;
    float s = g2[c] / sqrtf(v2[c] + EPS_);
    ws[WS_WDW + j] = wdw[j] * s;
    if (j % 9 == 0) ws[WS_B2 + c] = b2[c] - m2[c] * s;
  } else if (i < 5976 + C2) {
    int j = i - 5976;           // [0,216)
    float s = g3[j] / sqrtf(v3[j] + EPS_);
    ws[WS_INV3 + j] = s;
    ws[WS_T3 + j] = b3[j] - m3[j] * s;
  }
}

// 1x1 conv (240 -> 24) + BN1 -> t1, px=2 with a CORRECTLY-SIZED register cap.
// Block = 256 threads = 4 waves over the SAME 128 pixels; lane = 2 consecutive
// px; wave kq reduces ci in [60kq, 60kq+60); acc[24][2]. This is r1's exact
// compute body; r1 ran it UNCAPPED and the compiler picked 176 VGPR = one past
// the residency threshold -> latency-bound 72 us. Cap law (measured this
// session): actual cap = 256/arg2 ((512,6)->40, (256,3)->84 -- both BELOW the
// ~92-reg structural minimum -> spill disasters). (256,2) -> cap 128: above
// the minimum (no spill; allocator shallows prefetch instead) and >= 4
// waves/SIMD residency vs 3.06 waves/SIMD of work. px=2 halves the LDS
// broadcast term (the px=1 kernel's ~44 us floor) to ~22 us.
__global__ __launch_bounds__(256, 2) void conv1x1_kernel(
    const float* __restrict__ x, const float* __restrict__ wt,
    const float* __restrict__ bias1, float* __restrict__ t1b,
    const int cs, const int coff) {
  __shared__ float smem[12288];  // [0,5760) weights; then red[4][24][128]
  const int tid  = threadIdx.x;
  const int lane = tid & 63;
  const int kq   = tid >> 6;     // K-chunk 0..3

  for (int i = tid; i < 5760; i += 256) smem[i] = wt[i];
  __syncthreads();

  const int P   = blockIdx.x * 128 + lane * 2;  // global pixel pair
  const int b   = P / HW;
  const int hw  = P - b * HW;                   // even; never splits a batch
  const int ci0 = kq * 60;
  const float* xp    = x + ((size_t)b * CIN + ci0) * HW + hw;
  const float* wbase = smem + ci0 * C1;

  float acc[C1][2];
#pragma unroll
  for (int i = 0; i < C1; ++i) { acc[i][0] = 0.f; acc[i][1] = 0.f; }

  float2 A[6], B[6];
#pragma unroll
  for (int j = 0; j < 6; ++j) A[j] = *(const float2*)(xp + (size_t)j * HW);
#pragma unroll
  for (int j = 0; j < 6; ++j) B[j] = *(const float2*)(xp + (size_t)(6 + j) * HW);

  auto consume = [&](const float2* buf, int cb) {
#pragma unroll
    for (int j = 0; j < 6; ++j) {
      const float2 xv = buf[j];
      const float* wr = wbase + (cb + j) * C1;
#pragma unroll
      for (int k = 0; k < 6; ++k) {
        const float4 wq = *(const float4*)(wr + 4 * k);
        acc[4*k+0][0] = fmaf(wq.x, xv.x, acc[4*k+0][0]);
        acc[4*k+0][1] = fmaf(wq.x, xv.y, acc[4*k+0][1]);
        acc[4*k+1][0] = fmaf(wq.y, xv.x, acc[4*k+1][0]);
        acc[4*k+1][1] = fmaf(wq.y, xv.y, acc[4*k+1][1]);
        acc[4*k+2][0] = fmaf(wq.z, xv.x, acc[4*k+2][0]);
        acc[4*k+2][1] = fmaf(wq.z, xv.y, acc[4*k+2][1]);
        acc[4*k+3][0] = fmaf(wq.w, xv.x, acc[4*k+3][0]);
        acc[4*k+3][1] = fmaf(wq.w, xv.y, acc[4*k+3][1]);
      }
    }
  };

#pragma unroll 1
  for (int g = 0; g < 4; ++g) {
    const int c = 12 * g;
    consume(A, c);
#pragma unroll
    for (int j = 0; j < 6; ++j) A[j] = *(const float2*)(xp + (size_t)(c + 12 + j) * HW);
    consume(B, c + 6);
#pragma unroll
    for (int j = 0; j < 6; ++j) B[j] = *(const float2*)(xp + (size_t)(c + 18 + j) * HW);
  }
  consume(A, 48);
  consume(B, 54);
  __syncthreads();               // weights dead; smem -> red[4][24][128]

#pragma unroll
  for (int i = 0; i < C1; ++i)
    *(float2*)&smem[(kq * C1 + i) * 128 + 2 * lane] = make_float2(acc[i][0], acc[i][1]);
  __syncthreads();

  // wave kq finishes channels [6kq, 6kq+6)
  float* o = t1b + ((size_t)b * cs + coff) * HW + hw;
#pragma unroll
  for (int i = 0; i < 6; ++i) {
    const int co = kq * 6 + i;
    const float2 p0 = *(const float2*)&smem[(0 * C1 + co) * 128 + 2 * lane];
    const float2 p1 = *(const float2*)&smem[(1 * C1 + co) * 128 + 2 * lane];
    const float2 p2 = *(const float2*)&smem[(2 * C1 + co) * 128 + 2 * lane];
    const float2 p3 = *(const float2*)&smem[(3 * C1 + co) * 128 + 2 * lane];
    const float bsv = bias1[co];
    float2 v;
    v.x = p0.x + p1.x + p2.x + p3.x + bsv;
    v.y = p0.y + p1.y + p2.y + p3.y + bsv;
    *(float2*)(o + (size_t)co * HW) = v;
  }
}

// Fused depthwise 3x3 + BN2 and adder + BN3 + ReLU -- VERBATIM r1/r7 strip
// version (best measured dwadd: ~27 us; strips reach the 32-wave/CU cap).
__global__ __launch_bounds__(256) void dwadd_kernel(
    const float* __restrict__ t1b, const float* __restrict__ wdwf,
    const float* __restrict__ bias2, const float* __restrict__ wadd,
    const float* __restrict__ inv3, const float* __restrict__ t3,
    float* __restrict__ out) {
  const int c = blockIdx.y, b = blockIdx.z;
  const int h0 = blockIdx.x * 14;
  __shared__ __align__(16) float t1s[18 * 56];
  __shared__ __align__(16) float x1s[16 * 56];
  __shared__ float taps[R_][3][4];
  __shared__ float s3[R_], t3s[R_];
  const int tid = threadIdx.x;

  const float* t1 = t1b + ((size_t)b * C1 + c) * HW;
  // stage t1 strip as float4 (252 vectors, rows are 56 = 14*4 floats)
  if (tid < 252) {
    const int r  = tid / 14;
    const int w0 = (tid - r * 14) * 4;
    const int gh = h0 - 2 + r;
    float4 v = {0.f, 0.f, 0.f, 0.f};
    if (gh >= 0 && gh < H_) v = *(const float4*)(t1 + gh * W_ + w0);
    *(float4*)&t1s[r * 56 + w0] = v;
  }
  if (tid < 108) {
    int r = tid / 12, kh = (tid / 4) % 3, kw = tid & 3;
    taps[r][kh][kw] = (kw < 3) ? wadd[((c * R_ + r) * 3 + kh) * 3 + kw] : 0.f;
  } else if (tid >= 128 && tid < 128 + R_) {
    int r = tid - 128;
    s3[r]  = inv3[c * R_ + r];
    t3s[r] = t3[c * R_ + r];
  }
  float wk[9];
#pragma unroll
  for (int k = 0; k < 9; ++k) wk[k] = wdwf[c * 9 + k];  // uniform -> scalar
  const float bb = bias2[c];
  __syncthreads();

  // ---- dw phase: 224 quads = 16 rows (x1 rows h0-1 .. h0+14) x 14 quads ----
  if (tid < 224) {
    const int r  = tid / 14;            // local x1 row 0..15
    const int w0 = (tid - r * 14) * 4;
    const int gr = h0 - 1 + r;          // global x1 row
    float4 v = {bb, bb, bb, bb};
#pragma unroll
    for (int kh = 0; kh < 3; ++kh) {
      const float* rp = &t1s[(r + kh) * 56];   // t1 global row gr-1+kh
      const float  l  = (w0 > 0) ? rp[w0 - 1] : 0.f;
      const float4 m  = *(const float4*)(rp + w0);
      const float  rt = (w0 < 52) ? rp[w0 + 4] : 0.f;
      const float t0 = wk[kh * 3 + 0], t1w = wk[kh * 3 + 1], t2 = wk[kh * 3 + 2];
      v.x = fmaf(l,   t0, v.x); v.x = fmaf(m.x, t1w, v.x); v.x = fmaf(m.y, t2, v.x);
      v.y = fmaf(m.x, t0, v.y); v.y = fmaf(m.y, t1w, v.y); v.y = fmaf(m.z, t2, v.y);
      v.z = fmaf(m.y, t0, v.z); v.z = fmaf(m.z, t1w, v.z); v.z = fmaf(m.w, t2, v.z);
      v.w = fmaf(m.z, t0, v.w); v.w = fmaf(m.w, t1w, v.w); v.w = fmaf(rt,  t2, v.w);
    }
    float4 xv = v;
    if (gr < 0 || gr >= H_) { xv.x = 0.f; xv.y = 0.f; xv.z = 0.f; xv.w = 0.f; }
    *(float4*)&x1s[r * 56 + w0] = xv;   // zero-padded x1 (reference pads with 0)
    if (r >= 1 && r < 15)               // interior rows owned by this strip
      *(float4*)(out + ((size_t)b * COUT + c) * HW + gr * W_ + w0) = v;
  }
  __syncthreads();

  // ---- adder phase: 196 quads = 14 rows x 14 quads ----
  if (tid < 196) {
    const int r  = tid / 14;            // 0..13
    const int w0 = (tid - r * 14) * 4;
    const int gr = h0 + r;
    float xr[3][6];
#pragma unroll
    for (int kh = 0; kh < 3; ++kh) {
      const float* rp = &x1s[(r + kh) * 56];   // x1 global row gr-1+kh
      xr[kh][0] = (w0 > 0) ? rp[w0 - 1] : 0.f;
      const float4 m = *(const float4*)(rp + w0);
      xr[kh][1] = m.x; xr[kh][2] = m.y; xr[kh][3] = m.z; xr[kh][4] = m.w;
      xr[kh][5] = (w0 < 52) ? rp[w0 + 4] : 0.f;
    }
    float* ob = out + ((size_t)b * COUT + C1 + c * R_) * HW + gr * W_ + w0;
#pragma unroll
    for (int rr = 0; rr < R_; ++rr) {
      float a0 = 0.f, a1 = 0.f, a2 = 0.f, a3 = 0.f;
#pragma unroll
      for (int kh = 0; kh < 3; ++kh) {
#pragma unroll
        for (int kw = 0; kw < 3; ++kw) {
          const float t = taps[rr][kh][kw];
          a0 += fabsf(xr[kh][kw + 0] - t);
          a1 += fabsf(xr[kh][kw + 1] - t);
          a2 += fabsf(xr[kh][kw + 2] - t);
          a3 += fabsf(xr[kh][kw + 3] - t);
        }
      }
      const float s = s3[rr], tb = t3s[rr];
      float4 v;
      v.x = fmaxf(fmaf(-s, a0, tb), 0.f);
      v.y = fmaxf(fmaf(-s, a1, tb), 0.f);
      v.z = fmaxf(fmaf(-s, a2, tb), 0.f);
      v.w = fmaxf(fmaf(-s, a3, tb), 0.f);
      *(float4*)(ob + (size_t)rr * HW) = v;
    }
  }
}

// ---------- fallback path (t1 aliased into out ch [24,48)) ----------
// Used only if ws is too small to hold t1.

__global__ __launch_bounds__(256) void dw_kernel(
    const float* __restrict__ outr, const float* __restrict__ wdwf,
    const float* __restrict__ bias2, float* __restrict__ out) {
  const int c = blockIdx.y, b = blockIdx.z;
  const int q = blockIdx.x * 256 + threadIdx.x;   // quad id in [0,784)
  if (q >= 784) return;
  const int h  = q / 14;
  const int w0 = (q - h * 14) * 4;
  const float* in = outr + ((size_t)b * COUT + C1 + c) * HW;

  float wk[9];
#pragma unroll
  for (int k = 0; k < 9; ++k) wk[k] = wdwf[c * 9 + k];
  const float bb = bias2[c];

  float xr[3][6];
#pragma unroll
  for (int kh = 0; kh < 3; ++kh) {
    const int hh = h + kh - 1;
    const bool rok = (hh >= 0) & (hh < H_);
    const float* rp = in + hh * W_;
    xr[kh][0] = (rok && w0 > 0) ? rp[w0 - 1] : 0.f;
    if (rok) {
      const float4 m = *(const float4*)(rp + w0);
      xr[kh][1] = m.x; xr[kh][2] = m.y; xr[kh][3] = m.z; xr[kh][4] = m.w;
    } else {
      xr[kh][1] = 0.f; xr[kh][2] = 0.f; xr[kh][3] = 0.f; xr[kh][4] = 0.f;
    }
    xr[kh][5] = (rok && w0 < W_ - 4) ? rp[w0 + 4] : 0.f;
  }

  float4 v = {bb, bb, bb, bb};
#pragma unroll
  for (int kh = 0; kh < 3; ++kh) {
#pragma unroll
    for (int kw = 0; kw < 3; ++kw) {
      const float t = wk[kh * 3 + kw];
      v.x = fmaf(xr[kh][kw + 0], t, v.x);
      v.y = fmaf(xr[kh][kw + 1], t, v.y);
      v.z = fmaf(xr[kh][kw + 2], t, v.z);
      v.w = fmaf(xr[kh][kw + 3], t, v.w);
    }
  }
  *(float4*)(out + ((size_t)b * COUT + c) * HW + h * W_ + w0) = v;
}

__global__ __launch_bounds__(256) void adder_kernel(
    const float* __restrict__ outr, const float* __restrict__ wadd,
    const float* __restrict__ inv3, const float* __restrict__ t3,
    float* __restrict__ out) {
  const int c = blockIdx.y, b = blockIdx.z;
  __shared__ float taps[R_][3][4];
  __shared__ float s3[R_], t3s[R_];
  const int tid = threadIdx.x;
  if (tid < 108) {
    int r = tid / 12, kh = (tid / 4) % 3, kw = tid & 3;
    taps[r][kh][kw] = (kw < 3) ? wadd[((c * R_ + r) * 3 + kh) * 3 + kw] : 0.f;
  } else if (tid >= 128 && tid < 128 + R_) {
    int r = tid - 128;
    s3[r]  = inv3[c * R_ + r];
    t3s[r] = t3[c * R_ + r];
  }
  __syncthreads();

  const int q = blockIdx.x * 256 + tid;
  if (q >= 784) return;
  const int h  = q / 14;
  const int w0 = (q - h * 14) * 4;
  const float* in = outr + ((size_t)b * COUT + C1 + c) * HW;

  float xr[3][6];
#pragma unroll
  for (int kh = 0; kh < 3; ++kh) {
    const int hh = h + kh - 1;
    const bool rok = (hh >= 0) & (hh < H_);
    const float* rp = in + hh * W_;
    xr[kh][0] = (rok && w0 > 0) ? rp[w0 - 1] : 0.f;
    if (rok) {
      const float4 m = *(const float4*)(rp + w0);
      xr[kh][1] = m.x; xr[kh][2] = m.y; xr[kh][3] = m.z; xr[kh][4] = m.w;
    } else {
      xr[kh][1] = 0.f; xr[kh][2] = 0.f; xr[kh][3] = 0.f; xr[kh][4] = 0.f;
    }
    xr[kh][5] = (rok && w0 < W_ - 4) ? rp[w0 + 4] : 0.f;
  }

#pragma unroll
  for (int r = 0; r < R_; ++r) {
    float a0 = 0.f, a1 = 0.f, a2 = 0.f, a3 = 0.f;
#pragma unroll
    for (int kh = 0; kh < 3; ++kh) {
#pragma unroll
      for (int kw = 0; kw < 3; ++kw) {
        const float t = taps[r][kh][kw];
        a0 += fabsf(xr[kh][kw + 0] - t);
        a1 += fabsf(xr[kh][kw + 1] - t);
        a2 += fabsf(xr[kh][kw + 2] - t);
        a3 += fabsf(xr[kh][kw + 3] - t);
      }
    }
    const float s = s3[r], bb = t3s[r];
    float4 v;
    v.x = fmaxf(fmaf(-s, a0, bb), 0.f);
    v.y = fmaxf(fmaf(-s, a1, bb), 0.f);
    v.z = fmaxf(fmaf(-s, a2, bb), 0.f);
    v.w = fmaxf(fmaf(-s, a3, bb), 0.f);
    *(float4*)(out + ((size_t)b * COUT + C1 + c * R_ + r) * HW + h * W_ + w0) = v;
  }
}

extern "C" void kernel_launch(void* const* d_in, const int* in_sizes, int n_in,
                              void* d_out, int out_size, void* d_ws, size_t ws_size,
                              hipStream_t stream) {
  const float* x    = (const float*)d_in[0];
  const float* wp   = (const float*)d_in[1];
  const float* g1   = (const float*)d_in[2];
  const float* b1   = (const float*)d_in[3];
  const float* m1   = (const float*)d_in[4];
  const float* v1   = (const float*)d_in[5];
  const float* wdw  = (const float*)d_in[6];
  const float* g2   = (const float*)d_in[7];
  const float* b2   = (const float*)d_in[8];
  const float* m2   = (const float*)d_in[9];
  const float* v2   = (const float*)d_in[10];
  const float* wadd = (const float*)d_in[11];
  const float* g3   = (const float*)d_in[12];
  const float* b3   = (const float*)d_in[13];
  const float* m3   = (const float*)d_in[14];
  const float* v3   = (const float*)d_in[15];

  float* ws  = (float*)d_ws;
  float* out = (float*)d_out;

  // t1 placement: ws tensor (fused, race-free) if workspace is big enough,
  // else alias into out ch [24,48) and use the split dw/adder path.
  const bool fused = ws_size >= (size_t)WS_T1_FLOATS * sizeof(float);
  float* t1b;
  int cs, coff;
  if (fused) { t1b = ws + WS_T1; cs = C1;   coff = 0; }
  else       { t1b = out;        cs = COUT; coff = C1; }

  // fold BN params / transpose weights (~26 KB of ws)
  prep_kernel<<<25, 256, 0, stream>>>(wp, g1, b1, m1, v1, wdw, g2, b2, m2, v2,
                                      g3, b3, m3, v3, ws);

  // 1x1 conv + BN1 -> t1. 784 blocks x 128 px x 4 ci-split waves, px=2,
  // register cap 128 via (256,2).
  conv1x1_kernel<<<784, 256, 0, stream>>>(x, ws + WS_WT, ws + WS_B1,
                                          t1b, cs, coff);

  if (fused) {
    // dw 3x3 + BN2 and adder + BN3 + ReLU, strip-fused (r1 structure)
    dwadd_kernel<<<dim3(4, C1, BATCH), 256, 0, stream>>>(
        t1b, ws + WS_WDW, ws + WS_B2, wadd, ws + WS_INV3, ws + WS_T3, out);
  } else {
    dw_kernel<<<dim3(4, C1, BATCH), 256, 0, stream>>>(out, ws + WS_WDW,
                                                      ws + WS_B2, out);
    adder_kernel<<<dim3(4, C1, BATCH), 256, 0, stream>>>(out, wadd,
                                                         ws + WS_INV3,
                                                         ws + WS_T3, out);
  }
}

// Round 9
// 210.215 us; speedup vs baseline: 1.1433x; 1.1433x over previous
//
#include <hip/hip_runtime.h>

#define EPS_ 1e-5f
#define BATCH 32
#define CIN 240
#define H_ 56
#define W_ 56
#define HW 3136          // 56*56
#define C1 24            // init_c
#define R_ 9             // ratio-1
#define C2 216           // C1*R_
#define COUT 240

// ---- workspace layout (floats) ----
#define WS_WT   0        // [240][24]  conv1x1 weights, ci-major, BN1 scale folded
#define WS_B1   5760     // [24]       BN1 bias
#define WS_WDW  5784     // [24][9]    dw weights, BN2 scale folded
#define WS_B2   6000     // [24]       BN2 bias
#define WS_INV3 6024     // [216]
#define WS_T3   6240     // [216]
#define WS_T1   8192     // [32][24][3136] t1 tensor (9.63 MB) -- if ws_size permits
#define WS_T1_FLOATS (8192 + BATCH * C1 * HW)

// Fold BN params / transpose weights. Separate tiny dispatch (~3 us): r6
// proved folding this into conv1x1's staging loop perturbs conv's regalloc
// (VGPR 70->48, pipeline collapse, 50->77 us). Keep it separate forever.
__global__ __launch_bounds__(256) void prep_kernel(
    const float* __restrict__ wp,
    const float* __restrict__ g1, const float* __restrict__ b1,
    const float* __restrict__ m1, const float* __restrict__ v1,
    const float* __restrict__ wdw,
    const float* __restrict__ g2, const float* __restrict__ b2,
    const float* __restrict__ m2, const float* __restrict__ v2,
    const float* __restrict__ g3, const float* __restrict__ b3,
    const float* __restrict__ m3, const float* __restrict__ v3,
    float* __restrict__ ws) {
  int i = blockIdx.x * 256 + threadIdx.x;
  if (i < 5760) {
    // transpose w_primary (co-major [24][240]) -> ci-major [240][24], fold BN1
    int ci = i / C1, co = i % C1;
    float s = g1[co] / sqrtf(v1[co] + EPS_);
    ws[WS_WT + ci * C1 + co] = wp[co * CIN + ci] * s;
    if (ci == 0) ws[WS_B1 + co] = b1[co] - m1[co] * s;
  } else if (i < 5760 + C2) {
    int j = i - 5760;           // [0,216): c*9+k
    int c = j / 9;
    float s = g2[c] / sqrtf(v2[c] + EPS_);
    ws[WS_WDW + j] = wdw[j] * s;
    if (j % 9 == 0) ws[WS_B2 + c] = b2[c] - m2[c] * s;
  } else if (i < 5976 + C2) {
    int j = i - 5976;           // [0,216)
    float s = g3[j] / sqrtf(v3[j] + EPS_);
    ws[WS_INV3 + j] = s;
    ws[WS_T3 + j] = b3[j] - m3[j] * s;
  }
}

// 1x1 conv (240 -> 24) + BN1 -> t1. VERBATIM r0/r4/r7 body (measured ~50 us
// three times; at the px=1 LDS-broadcast floor). Block = 256 threads = 4
// waves over the SAME 64 pixels; lane = 1 pixel. Wave kq reduces ci in
// [60kq, 60kq+60); acc[24]/thread (~70 VGPR natural; NO launch-bounds cap).
// px=2 abandoned after exhausting the cap lattice: uncapped->176 (latency,
// 72us), cap128->spill (76us), cap85->spill (154us), cap42->disaster (128us);
// the viable 129-175 window is unreachable (cap = 256/arg2 quantization).
__global__ __launch_bounds__(256) void conv1x1_kernel(
    const float* __restrict__ x, const float* __restrict__ wt,
    const float* __restrict__ bias1, float* __restrict__ t1b,
    const int cs, const int coff) {
  __shared__ float smem[6144];   // [0,5760) weights; then red[4][24][64]
  const int tid  = threadIdx.x;
  const int lane = tid & 63;
  const int kq   = tid >> 6;     // K-chunk 0..3

  for (int i = tid; i < 5760; i += 256) smem[i] = wt[i];
  __syncthreads();

  const int P   = blockIdx.x * 64 + lane;   // global pixel; 49 blocks/batch
  const int b   = P / HW;
  const int hw  = P - b * HW;
  const int ci0 = kq * 60;
  const float* xp    = x + ((size_t)b * CIN + ci0) * HW + hw;
  const float* wbase = smem + ci0 * C1;

  float acc[C1];
#pragma unroll
  for (int i = 0; i < C1; ++i) acc[i] = 0.f;

  float A[6], B[6];
#pragma unroll
  for (int j = 0; j < 6; ++j) A[j] = xp[(size_t)j * HW];
#pragma unroll
  for (int j = 0; j < 6; ++j) B[j] = xp[(size_t)(6 + j) * HW];

  auto consume = [&](const float* buf, int cb) {
#pragma unroll
    for (int j = 0; j < 6; ++j) {
      const float xv = buf[j];
      const float* wr = wbase + (cb + j) * C1;
#pragma unroll
      for (int k = 0; k < 6; ++k) {
        const float4 wq = *(const float4*)(wr + 4 * k);
        acc[4*k+0] = fmaf(wq.x, xv, acc[4*k+0]);
        acc[4*k+1] = fmaf(wq.y, xv, acc[4*k+1]);
        acc[4*k+2] = fmaf(wq.z, xv, acc[4*k+2]);
        acc[4*k+3] = fmaf(wq.w, xv, acc[4*k+3]);
      }
    }
  };

#pragma unroll 1
  for (int g = 0; g < 4; ++g) {
    const int c = 12 * g;
    consume(A, c);
#pragma unroll
    for (int j = 0; j < 6; ++j) A[j] = xp[(size_t)(c + 12 + j) * HW];
    consume(B, c + 6);
#pragma unroll
    for (int j = 0; j < 6; ++j) B[j] = xp[(size_t)(c + 18 + j) * HW];
  }
  consume(A, 48);
  consume(B, 54);
  __syncthreads();               // weights dead; smem -> red[4][24][64]

#pragma unroll
  for (int i = 0; i < C1; ++i) smem[(kq * C1 + i) * 64 + lane] = acc[i];
  __syncthreads();

  // wave kq finishes channels [6kq, 6kq+6)
  float* o = t1b + ((size_t)b * cs + coff) * HW + hw;
#pragma unroll
  for (int i = 0; i < 6; ++i) {
    const int co = kq * 6 + i;
    float v = smem[(0 * C1 + co) * 64 + lane]
            + smem[(1 * C1 + co) * 64 + lane]
            + smem[(2 * C1 + co) * 64 + lane]
            + smem[(3 * C1 + co) * 64 + lane]
            + bias1[co];
    o[(size_t)co * HW] = v;
  }
}

// Fused depthwise 3x3 + BN2 and adder + BN3 + ReLU -- VERBATIM r1/r7 strip
// version (best measured dwadd: ~27 us; strips reach the 32-wave/CU cap,
// full-channel was grid-limited to 24 waves/CU and ~20 us slower).
__global__ __launch_bounds__(256) void dwadd_kernel(
    const float* __restrict__ t1b, const float* __restrict__ wdwf,
    const float* __restrict__ bias2, const float* __restrict__ wadd,
    const float* __restrict__ inv3, const float* __restrict__ t3,
    float* __restrict__ out) {
  const int c = blockIdx.y, b = blockIdx.z;
  const int h0 = blockIdx.x * 14;
  __shared__ __align__(16) float t1s[18 * 56];
  __shared__ __align__(16) float x1s[16 * 56];
  __shared__ float taps[R_][3][4];
  __shared__ float s3[R_], t3s[R_];
  const int tid = threadIdx.x;

  const float* t1 = t1b + ((size_t)b * C1 + c) * HW;
  // stage t1 strip as float4 (252 vectors, rows are 56 = 14*4 floats)
  if (tid < 252) {
    const int r  = tid / 14;
    const int w0 = (tid - r * 14) * 4;
    const int gh = h0 - 2 + r;
    float4 v = {0.f, 0.f, 0.f, 0.f};
    if (gh >= 0 && gh < H_) v = *(const float4*)(t1 + gh * W_ + w0);
    *(float4*)&t1s[r * 56 + w0] = v;
  }
  if (tid < 108) {
    int r = tid / 12, kh = (tid / 4) % 3, kw = tid & 3;
    taps[r][kh][kw] = (kw < 3) ? wadd[((c * R_ + r) * 3 + kh) * 3 + kw] : 0.f;
  } else if (tid >= 128 && tid < 128 + R_) {
    int r = tid - 128;
    s3[r]  = inv3[c * R_ + r];
    t3s[r] = t3[c * R_ + r];
  }
  float wk[9];
#pragma unroll
  for (int k = 0; k < 9; ++k) wk[k] = wdwf[c * 9 + k];  // uniform -> scalar
  const float bb = bias2[c];
  __syncthreads();

  // ---- dw phase: 224 quads = 16 rows (x1 rows h0-1 .. h0+14) x 14 quads ----
  if (tid < 224) {
    const int r  = tid / 14;            // local x1 row 0..15
    const int w0 = (tid - r * 14) * 4;
    const int gr = h0 - 1 + r;          // global x1 row
    float4 v = {bb, bb, bb, bb};
#pragma unroll
    for (int kh = 0; kh < 3; ++kh) {
      const float* rp = &t1s[(r + kh) * 56];   // t1 global row gr-1+kh
      const float  l  = (w0 > 0) ? rp[w0 - 1] : 0.f;
      const float4 m  = *(const float4*)(rp + w0);
      const float  rt = (w0 < 52) ? rp[w0 + 4] : 0.f;
      const float t0 = wk[kh * 3 + 0], t1w = wk[kh * 3 + 1], t2 = wk[kh * 3 + 2];
      v.x = fmaf(l,   t0, v.x); v.x = fmaf(m.x, t1w, v.x); v.x = fmaf(m.y, t2, v.x);
      v.y = fmaf(m.x, t0, v.y); v.y = fmaf(m.y, t1w, v.y); v.y = fmaf(m.z, t2, v.y);
      v.z = fmaf(m.y, t0, v.z); v.z = fmaf(m.z, t1w, v.z); v.z = fmaf(m.w, t2, v.z);
      v.w = fmaf(m.z, t0, v.w); v.w = fmaf(m.w, t1w, v.w); v.w = fmaf(rt,  t2, v.w);
    }
    float4 xv = v;
    if (gr < 0 || gr >= H_) { xv.x = 0.f; xv.y = 0.f; xv.z = 0.f; xv.w = 0.f; }
    *(float4*)&x1s[r * 56 + w0] = xv;   // zero-padded x1 (reference pads with 0)
    if (r >= 1 && r < 15)               // interior rows owned by this strip
      *(float4*)(out + ((size_t)b * COUT + c) * HW + gr * W_ + w0) = v;
  }
  __syncthreads();

  // ---- adder phase: 196 quads = 14 rows x 14 quads ----
  if (tid < 196) {
    const int r  = tid / 14;            // 0..13
    const int w0 = (tid - r * 14) * 4;
    const int gr = h0 + r;
    float xr[3][6];
#pragma unroll
    for (int kh = 0; kh < 3; ++kh) {
      const float* rp = &x1s[(r + kh) * 56];   // x1 global row gr-1+kh
      xr[kh][0] = (w0 > 0) ? rp[w0 - 1] : 0.f;
      const float4 m = *(const float4*)(rp + w0);
      xr[kh][1] = m.x; xr[kh][2] = m.y; xr[kh][3] = m.z; xr[kh][4] = m.w;
      xr[kh][5] = (w0 < 52) ? rp[w0 + 4] : 0.f;
    }
    float* ob = out + ((size_t)b * COUT + C1 + c * R_) * HW + gr * W_ + w0;
#pragma unroll
    for (int rr = 0; rr < R_; ++rr) {
      float a0 = 0.f, a1 = 0.f, a2 = 0.f, a3 = 0.f;
#pragma unroll
      for (int kh = 0; kh < 3; ++kh) {
#pragma unroll
        for (int kw = 0; kw < 3; ++kw) {
          const float t = taps[rr][kh][kw];
          a0 += fabsf(xr[kh][kw + 0] - t);
          a1 += fabsf(xr[kh][kw + 1] - t);
          a2 += fabsf(xr[kh][kw + 2] - t);
          a3 += fabsf(xr[kh][kw + 3] - t);
        }
      }
      const float s = s3[rr], tb = t3s[rr];
      float4 v;
      v.x = fmaxf(fmaf(-s, a0, tb), 0.f);
      v.y = fmaxf(fmaf(-s, a1, tb), 0.f);
      v.z = fmaxf(fmaf(-s, a2, tb), 0.f);
      v.w = fmaxf(fmaf(-s, a3, tb), 0.f);
      *(float4*)(ob + (size_t)rr * HW) = v;
    }
  }
}

// ---------- fallback path (t1 aliased into out ch [24,48)) ----------
// Used only if ws is too small to hold t1.

__global__ __launch_bounds__(256) void dw_kernel(
    const float* __restrict__ outr, const float* __restrict__ wdwf,
    const float* __restrict__ bias2, float* __restrict__ out) {
  const int c = blockIdx.y, b = blockIdx.z;
  const int q = blockIdx.x * 256 + threadIdx.x;   // quad id in [0,784)
  if (q >= 784) return;
  const int h  = q / 14;
  const int w0 = (q - h * 14) * 4;
  const float* in = outr + ((size_t)b * COUT + C1 + c) * HW;

  float wk[9];
#pragma unroll
  for (int k = 0; k < 9; ++k) wk[k] = wdwf[c * 9 + k];
  const float bb = bias2[c];

  float xr[3][6];
#pragma unroll
  for (int kh = 0; kh < 3; ++kh) {
    const int hh = h + kh - 1;
    const bool rok = (hh >= 0) & (hh < H_);
    const float* rp = in + hh * W_;
    xr[kh][0] = (rok && w0 > 0) ? rp[w0 - 1] : 0.f;
    if (rok) {
      const float4 m = *(const float4*)(rp + w0);
      xr[kh][1] = m.x; xr[kh][2] = m.y; xr[kh][3] = m.z; xr[kh][4] = m.w;
    } else {
      xr[kh][1] = 0.f; xr[kh][2] = 0.f; xr[kh][3] = 0.f; xr[kh][4] = 0.f;
    }
    xr[kh][5] = (rok && w0 < W_ - 4) ? rp[w0 + 4] : 0.f;
  }

  float4 v = {bb, bb, bb, bb};
#pragma unroll
  for (int kh = 0; kh < 3; ++kh) {
#pragma unroll
    for (int kw = 0; kw < 3; ++kw) {
      const float t = wk[kh * 3 + kw];
      v.x = fmaf(xr[kh][kw + 0], t, v.x);
      v.y = fmaf(xr[kh][kw + 1], t, v.y);
      v.z = fmaf(xr[kh][kw + 2], t, v.z);
      v.w = fmaf(xr[kh][kw + 3], t, v.w);
    }
  }
  *(float4*)(out + ((size_t)b * COUT + c) * HW + h * W_ + w0) = v;
}

__global__ __launch_bounds__(256) void adder_kernel(
    const float* __restrict__ outr, const float* __restrict__ wadd,
    const float* __restrict__ inv3, const float* __restrict__ t3,
    float* __restrict__ out) {
  const int c = blockIdx.y, b = blockIdx.z;
  __shared__ float taps[R_][3][4];
  __shared__ float s3[R_], t3s[R_];
  const int tid = threadIdx.x;
  if (tid < 108) {
    int r = tid / 12, kh = (tid / 4) % 3, kw = tid & 3;
    taps[r][kh][kw] = (kw < 3) ? wadd[((c * R_ + r) * 3 + kh) * 3 + kw] : 0.f;
  } else if (tid >= 128 && tid < 128 + R_) {
    int r = tid - 128;
    s3[r]  = inv3[c * R_ + r];
    t3s[r] = t3[c * R_ + r];
  }
  __syncthreads();

  const int q = blockIdx.x * 256 + tid;
  if (q >= 784) return;
  const int h  = q / 14;
  const int w0 = (q - h * 14) * 4;
  const float* in = outr + ((size_t)b * COUT + C1 + c) * HW;

  float xr[3][6];
#pragma unroll
  for (int kh = 0; kh < 3; ++kh) {
    const int hh = h + kh - 1;
    const bool rok = (hh >= 0) & (hh < H_);
    const float* rp = in + hh * W_;
    xr[kh][0] = (rok && w0 > 0) ? rp[w0 - 1] : 0.f;
    if (rok) {
      const float4 m = *(const float4*)(rp + w0);
      xr[kh][1] = m.x; xr[kh][2] = m.y; xr[kh][3] = m.z; xr[kh][4] = m.w;
    } else {
      xr[kh][1] = 0.f; xr[kh][2] = 0.f; xr[kh][3] = 0.f; xr[kh][4] = 0.f;
    }
    xr[kh][5] = (rok && w0 < W_ - 4) ? rp[w0 + 4] : 0.f;
  }

#pragma unroll
  for (int r = 0; r < R_; ++r) {
    float a0 = 0.f, a1 = 0.f, a2 = 0.f, a3 = 0.f;
#pragma unroll
    for (int kh = 0; kh < 3; ++kh) {
#pragma unroll
      for (int kw = 0; kw < 3; ++kw) {
        const float t = taps[r][kh][kw];
        a0 += fabsf(xr[kh][kw + 0] - t);
        a1 += fabsf(xr[kh][kw + 1] - t);
        a2 += fabsf(xr[kh][kw + 2] - t);
        a3 += fabsf(xr[kh][kw + 3] - t);
      }
    }
    const float s = s3[r], bb = t3s[r];
    float4 v;
    v.x = fmaxf(fmaf(-s, a0, bb), 0.f);
    v.y = fmaxf(fmaf(-s, a1, bb), 0.f);
    v.z = fmaxf(fmaf(-s, a2, bb), 0.f);
    v.w = fmaxf(fmaf(-s, a3, bb), 0.f);
    *(float4*)(out + ((size_t)b * COUT + C1 + c * R_ + r) * HW + h * W_ + w0) = v;
  }
}

extern "C" void kernel_launch(void* const* d_in, const int* in_sizes, int n_in,
                              void* d_out, int out_size, void* d_ws, size_t ws_size,
                              hipStream_t stream) {
  const float* x    = (const float*)d_in[0];
  const float* wp   = (const float*)d_in[1];
  const float* g1   = (const float*)d_in[2];
  const float* b1   = (const float*)d_in[3];
  const float* m1   = (const float*)d_in[4];
  const float* v1   = (const float*)d_in[5];
  const float* wdw  = (const float*)d_in[6];
  const float* g2   = (const float*)d_in[7];
  const float* b2   = (const float*)d_in[8];
  const float* m2   = (const float*)d_in[9];
  const float* v2   = (const float*)d_in[10];
  const float* wadd = (const float*)d_in[11];
  const float* g3   = (const float*)d_in[12];
  const float* b3   = (const float*)d_in[13];
  const float* m3   = (const float*)d_in[14];
  const float* v3   = (const float*)d_in[15];

  float* ws  = (float*)d_ws;
  float* out = (float*)d_out;

  // t1 placement: ws tensor (fused, race-free) if workspace is big enough,
  // else alias into out ch [24,48) and use the split dw/adder path.
  const bool fused = ws_size >= (size_t)WS_T1_FLOATS * sizeof(float);
  float* t1b;
  int cs, coff;
  if (fused) { t1b = ws + WS_T1; cs = C1;   coff = 0; }
  else       { t1b = out;        cs = COUT; coff = C1; }

  // fold BN params / transpose weights (~26 KB of ws)
  prep_kernel<<<25, 256, 0, stream>>>(wp, g1, b1, m1, v1, wdw, g2, b2, m2, v2,
                                      g3, b3, m3, v3, ws);

  // 1x1 conv + BN1 -> t1. 1568 blocks x 64 px x 4 ci-split waves (r0-exact).
  conv1x1_kernel<<<1568, 256, 0, stream>>>(x, ws + WS_WT, ws + WS_B1,
                                           t1b, cs, coff);

  if (fused) {
    // dw 3x3 + BN2 and adder + BN3 + ReLU, strip-fused (r1 structure)
    dwadd_kernel<<<dim3(4, C1, BATCH), 256, 0, stream>>>(
        t1b, ws + WS_WDW, ws + WS_B2, wadd, ws + WS_INV3, ws + WS_T3, out);
  } else {
    dw_kernel<<<dim3(4, C1, BATCH), 256, 0, stream>>>(out, ws + WS_WDW,
                                                      ws + WS_B2, out);
    adder_kernel<<<dim3(4, C1, BATCH), 256, 0, stream>>>(out, wadd,
                                                         ws + WS_INV3,
                                                         ws + WS_T3, out);
  }
}